// Round 2
// baseline (2795.771 us; speedup 1.0000x reference)
//
#include <hip/hip_runtime.h>

// ---------------------------------------------------------------- constants
#define EPSV 1e-5f
constexpr int Bsz = 4, T0 = 512, Dm = 512, TT = 513, NHh = 8, KK = 4;
constexpr int IN = 1024, DHd = 128, NCc = 1000;
constexpr int ROWS = Bsz * TT; // 2052

__device__ __forceinline__ float siluf(float x) { return x / (1.f + __expf(-x)); }

// ---------------------------------------------------------------- concat x + cls
__global__ __launch_bounds__(256) void concat_kernel(const float* __restrict__ x,
                                                     const float* __restrict__ cls,
                                                     float* __restrict__ h) {
    int idx = blockIdx.x * 256 + threadIdx.x;
    if (idx >= Bsz * TT * Dm) return;
    int d = idx & (Dm - 1);
    int bt = idx >> 9;
    int t = bt % TT, b = bt / TT;
    h[idx] = (t < T0) ? x[((size_t)(b * T0 + t)) * Dm + d] : cls[d];
}

// ---------------------------------------------------------------- LayerNorm rows of D=512
__global__ __launch_bounds__(256) void ln_kernel(const float* __restrict__ in,
                                                 const float* __restrict__ s,
                                                 const float* __restrict__ bb,
                                                 float* __restrict__ out) {
    int row = blockIdx.x, tid = threadIdx.x;
    const float* r = in + (size_t)row * Dm;
    __shared__ float s1[4], s2[4];
    float x0 = r[tid], x1 = r[tid + 256];
    float sum = x0 + x1, sq = x0 * x0 + x1 * x1;
#pragma unroll
    for (int o = 32; o > 0; o >>= 1) { sum += __shfl_xor(sum, o); sq += __shfl_xor(sq, o); }
    if ((tid & 63) == 0) { s1[tid >> 6] = sum; s2[tid >> 6] = sq; }
    __syncthreads();
    sum = s1[0] + s1[1] + s1[2] + s1[3];
    sq  = s2[0] + s2[1] + s2[2] + s2[3];
    float mu = sum / Dm, var = sq / Dm - mu * mu, inv = rsqrtf(var + EPSV);
    out[(size_t)row * Dm + tid]       = (x0 - mu) * inv * s[tid] + bb[tid];
    out[(size_t)row * Dm + tid + 256] = (x1 - mu) * inv * s[tid + 256] + bb[tid + 256];
}

// ---------------------------------------------------------------- generic f32 GEMM: C = scale*(A@W) (+bias) (+resid)
// A: f32 MxK (leading dim lda), W: f32 KxN (leading dim ldw), 64x64 tile, 256 threads
__global__ __launch_bounds__(256) void gemm_kernel(const float* __restrict__ A, int lda,
                                                   const float* __restrict__ W, int ldw,
                                                   const float* __restrict__ bias,
                                                   const float* __restrict__ resid, int ldr,
                                                   float* __restrict__ Cout, int ldc,
                                                   int M, int Kd, float scale) {
    __shared__ __align__(16) float As[16][68];
    __shared__ __align__(16) float Bs[16][64];
    int tid = threadIdx.x;
    int tx = tid & 15, ty = tid >> 4;
    int m0 = blockIdx.y * 64, n0 = blockIdx.x * 64;
    int arow = tid >> 2, akp = (tid & 3) * 4;
    int brow = tid >> 4, bnp = (tid & 15) * 4;
    float acc[4][4] = {};
    for (int k0 = 0; k0 < Kd; k0 += 16) {
        float4 av = make_float4(0.f, 0.f, 0.f, 0.f);
        int gm = m0 + arow;
        if (gm < M) av = *(const float4*)(A + (size_t)gm * lda + k0 + akp);
        As[akp + 0][arow] = av.x; As[akp + 1][arow] = av.y;
        As[akp + 2][arow] = av.z; As[akp + 3][arow] = av.w;
        float4 wv = *(const float4*)(W + (size_t)(k0 + brow) * ldw + n0 + bnp);
        Bs[brow][bnp + 0] = wv.x; Bs[brow][bnp + 1] = wv.y;
        Bs[brow][bnp + 2] = wv.z; Bs[brow][bnp + 3] = wv.w;
        __syncthreads();
#pragma unroll
        for (int k = 0; k < 16; k++) {
            float4 a  = *(const float4*)&As[k][ty * 4];
            float4 bv = *(const float4*)&Bs[k][tx * 4];
            float aa[4] = {a.x, a.y, a.z, a.w};
            float bb2[4] = {bv.x, bv.y, bv.z, bv.w};
#pragma unroll
            for (int i = 0; i < 4; i++)
#pragma unroll
                for (int j = 0; j < 4; j++) acc[i][j] += aa[i] * bb2[j];
        }
        __syncthreads();
    }
#pragma unroll
    for (int i = 0; i < 4; i++) {
        int gm = m0 + ty * 4 + i;
        if (gm >= M) continue;
        float* crow = Cout + (size_t)gm * ldc + n0 + tx * 4;
        const float* rrow = resid ? (resid + (size_t)gm * ldr + n0 + tx * 4) : nullptr;
#pragma unroll
        for (int j = 0; j < 4; j++) {
            float vsum = acc[i][j] * scale;
            if (bias) vsum += bias[n0 + tx * 4 + j];
            if (rrow) vsum += rrow[j];
            crow[j] = vsum;
        }
    }
}

// ---------------------------------------------------------------- causal depthwise conv (K=4) + SiLU
__global__ __launch_bounds__(256) void conv_silu_kernel(const float* __restrict__ up,
                                                        const float* __restrict__ ck,
                                                        const float* __restrict__ cb,
                                                        float* __restrict__ xc) {
    int idx = blockIdx.x * 256 + threadIdx.x;
    if (idx >= ROWS * IN) return;
    int c = idx & (IN - 1);
    int bt = idx >> 10;
    int t = bt % TT, b = bt / TT;
    float acc = cb[c];
#pragma unroll
    for (int j = 0; j < KK; j++) {
        int tt = t - (KK - 1) + j;
        if (tt >= 0) acc += up[((size_t)(b * TT + tt)) * (2 * IN) + c] * ck[c * KK + j];
    }
    xc[idx] = siluf(acc);
}

// ---------------------------------------------------------------- input/forget gate projections (N=8 each)
__global__ __launch_bounds__(256) void gates_kernel(const float* __restrict__ xc,
                                                    const float* __restrict__ wig, const float* __restrict__ big,
                                                    const float* __restrict__ wfg, const float* __restrict__ bfg,
                                                    float* __restrict__ ip, float* __restrict__ fp) {
    int row = blockIdx.x, tid = threadIdx.x;
    __shared__ float sx[IN];
    for (int i = tid; i < IN; i += 256) sx[i] = xc[(size_t)row * IN + i];
    __syncthreads();
    int g = tid >> 4, l = tid & 15;
    const float* w = (g < 8) ? wig : wfg;
    int h = g & 7;
    float acc = 0.f;
    for (int kk = l; kk < IN; kk += 16) acc += sx[kk] * w[kk * NHh + h];
#pragma unroll
    for (int o = 8; o > 0; o >>= 1) acc += __shfl_down(acc, o, 16);
    if (l == 0) {
        if (g < 8) ip[(size_t)row * NHh + h] = acc + big[h];
        else       fp[(size_t)row * NHh + h] = acc + bfg[h];
    }
}

// ---------------------------------------------------------------- sequential mLSTM scan: 1 workgroup per (b,h)
__global__ __launch_bounds__(256) void scan_kernel(const float* __restrict__ q,
                                                   const float* __restrict__ k,
                                                   const float* __restrict__ v,
                                                   const float* __restrict__ ip,
                                                   const float* __restrict__ fp,
                                                   float* __restrict__ hs) {
    int b = blockIdx.x >> 3, h = blockIdx.x & 7;
    int tid = threadIdx.x;
    int row = tid >> 1, cb = (tid & 1) * 64;
    float C[64];
#pragma unroll
    for (int j = 0; j < 64; j++) C[j] = 0.f;
    float nown = 0.f, m = 0.f;
    __shared__ __align__(16) float sq[128], sk[128], sv[128];
    __shared__ float sred[4];
    for (int t = 0; t < TT; t++) {
        size_t base = ((size_t)(b * TT + t)) * IN + h * DHd;
        if (tid < 128) {
            sq[tid] = q[base + tid];
            sk[tid] = k[base + tid];
            sv[tid] = v[base + tid];
        }
        float ipv = ip[(size_t)(b * TT + t) * NHh + h];
        float fpv = fp[(size_t)(b * TT + t) * NHh + h];
        __syncthreads();
        // log_sigmoid (stable), online max-state
        float fl = (fpv >= 0.f) ? -log1pf(__expf(-fpv)) : (fpv - log1pf(__expf(fpv)));
        float mnew = fmaxf(fl + m, ipv);
        float iw = __expf(ipv - mnew);
        float fw = __expf(fl + m - mnew);
        m = mnew;
        float ivr = iw * sv[row];
        float hp = 0.f;
        const float4* k4 = (const float4*)(sk + cb);
        const float4* q4 = (const float4*)(sq + cb);
#pragma unroll
        for (int j = 0; j < 16; j++) {
            float4 kv = k4[j], qv = q4[j];
            C[4 * j + 0] = fw * C[4 * j + 0] + ivr * kv.x; hp += C[4 * j + 0] * qv.x;
            C[4 * j + 1] = fw * C[4 * j + 1] + ivr * kv.y; hp += C[4 * j + 1] * qv.y;
            C[4 * j + 2] = fw * C[4 * j + 2] + ivr * kv.z; hp += C[4 * j + 2] * qv.z;
            C[4 * j + 3] = fw * C[4 * j + 3] + ivr * kv.w; hp += C[4 * j + 3] * qv.w;
        }
        // n (duplicated across the thread pair owning a row)
        nown = fw * nown + iw * sk[row];
        float term = nown * sq[row]; // each row term counted twice -> *0.5 below
#pragma unroll
        for (int o = 32; o > 0; o >>= 1) term += __shfl_xor(term, o);
        if ((tid & 63) == 0) sred[tid >> 6] = term;
        __syncthreads();
        float denom = (sred[0] + sred[1] + sred[2] + sred[3]) * 0.5f;
        denom = fmaxf(fabsf(denom), 1.f);
        float hpair = hp + __shfl_xor(hp, 1);
        if ((tid & 1) == 0) hs[base + row] = hpair / denom;
        __syncthreads();
    }
}

// ---------------------------------------------------------------- per-head norm * hn_s * silu(z)
__global__ __launch_bounds__(64) void headnorm_kernel(const float* __restrict__ hs,
                                                      const float* __restrict__ hn,
                                                      const float* __restrict__ up,
                                                      float* __restrict__ out) {
    int idx = blockIdx.x;
    int h = idx & 7, bt = idx >> 3;
    int tid = threadIdx.x;
    size_t base = (size_t)bt * IN + h * DHd;
    float x0 = hs[base + tid], x1 = hs[base + 64 + tid];
    float sum = x0 + x1, sq = x0 * x0 + x1 * x1;
#pragma unroll
    for (int o = 32; o > 0; o >>= 1) { sum += __shfl_xor(sum, o); sq += __shfl_xor(sq, o); }
    float mu = sum / DHd, var = sq / DHd - mu * mu, inv = rsqrtf(var + EPSV);
    size_t zb = (size_t)bt * (2 * IN) + IN + h * DHd;
    out[base + tid]      = (x0 - mu) * inv * hn[h * DHd + tid]      * siluf(up[zb + tid]);
    out[base + 64 + tid] = (x1 - mu) * inv * hn[h * DHd + 64 + tid] * siluf(up[zb + 64 + tid]);
}

// ---------------------------------------------------------------- final classifier head
__global__ __launch_bounds__(256) void classifier_kernel(const float* __restrict__ hbuf,
                                                         const float* __restrict__ s, const float* __restrict__ bb,
                                                         const float* __restrict__ fw, const float* __restrict__ fb,
                                                         float* __restrict__ out) {
    int b = blockIdx.x, tid = threadIdx.x;
    const float* r = hbuf + ((size_t)b * TT + TT - 1) * Dm;
    __shared__ float vbuf[Dm];
    __shared__ float s1[4], s2[4];
    float x0 = r[tid], x1 = r[tid + 256];
    float sum = x0 + x1, sq = x0 * x0 + x1 * x1;
#pragma unroll
    for (int o = 32; o > 0; o >>= 1) { sum += __shfl_xor(sum, o); sq += __shfl_xor(sq, o); }
    if ((tid & 63) == 0) { s1[tid >> 6] = sum; s2[tid >> 6] = sq; }
    __syncthreads();
    sum = s1[0] + s1[1] + s1[2] + s1[3];
    sq  = s2[0] + s2[1] + s2[2] + s2[3];
    float mu = sum / Dm, var = sq / Dm - mu * mu, inv = rsqrtf(var + EPSV);
    float n0 = (x0 - mu) * inv * s[tid] + bb[tid];
    float n1 = (x1 - mu) * inv * s[tid + 256] + bb[tid + 256];
    vbuf[tid] = fmaxf(n0, 0.f);
    vbuf[tid + 256] = fmaxf(n1, 0.f);
    __syncthreads();
    for (int j = tid; j < NCc; j += 256) {
        float acc = fb[j];
        for (int kk = 0; kk < Dm; kk++) acc += vbuf[kk] * fw[kk * NCc + j];
        out[b * NCc + j] = acc;
    }
}

// ---------------------------------------------------------------- launch
extern "C" void kernel_launch(void* const* d_in, const int* in_sizes, int n_in,
                              void* d_out, int out_size, void* d_ws, size_t ws_size,
                              hipStream_t stream) {
    const float* x      = (const float*)d_in[0];
    const float* cls    = (const float*)d_in[1];
    const float* ln_s   = (const float*)d_in[2];
    const float* ln_b   = (const float*)d_in[3];
    const float* w_up   = (const float*)d_in[4];
    const float* b_up   = (const float*)d_in[5];
    const float* conv_k = (const float*)d_in[6];
    const float* conv_b = (const float*)d_in[7];
    const float* w_q    = (const float*)d_in[8];
    const float* w_k    = (const float*)d_in[9];
    const float* w_v    = (const float*)d_in[10];
    const float* w_ig   = (const float*)d_in[11];
    const float* b_ig   = (const float*)d_in[12];
    const float* w_fg   = (const float*)d_in[13];
    const float* b_fg   = (const float*)d_in[14];
    const float* hn_s   = (const float*)d_in[15];
    const float* w_down = (const float*)d_in[16];
    const float* b_down = (const float*)d_in[17];
    const float* fcls   = (const float*)d_in[18];
    const float* fclb   = (const float*)d_in[19];
    const float* fc_w   = (const float*)d_in[20];
    const float* fc_b   = (const float*)d_in[21];
    float* out = (float*)d_out;

    float* ws = (float*)d_ws;
    size_t off = 0;
    float* f_h  = ws + off; off += (size_t)ROWS * Dm;       // 1,050,624
    float* f_xn = ws + off; off += (size_t)ROWS * Dm;
    float* f_up = ws + off; off += (size_t)ROWS * 2 * IN;   // 4,202,496
    float* f_xc = ws + off; off += (size_t)ROWS * IN;
    float* f_q  = ws + off; off += (size_t)ROWS * IN;
    float* f_k  = ws + off; off += (size_t)ROWS * IN;
    float* f_v  = ws + off; off += (size_t)ROWS * IN;
    float* f_hs = ws + off; off += (size_t)ROWS * IN;
    float* f_ip = ws + off; off += (size_t)ROWS * NHh;
    float* f_fp = ws + off; off += (size_t)ROWS * NHh;

    const float kscale = 0.08838834764831845f; // DH^-0.5

    concat_kernel<<<(ROWS * Dm + 255) / 256, 256, 0, stream>>>(x, cls, f_h);

    for (int blk = 0; blk < 2; blk++) {
        const float* p_ln_s = ln_s + blk * Dm;
        const float* p_ln_b = ln_b + blk * Dm;
        const float* p_wup  = w_up + (size_t)blk * Dm * 2 * IN;
        const float* p_bup  = b_up + (size_t)blk * 2 * IN;
        const float* p_ck   = conv_k + (size_t)blk * IN * KK;
        const float* p_cb   = conv_b + (size_t)blk * IN;
        const float* p_wq   = w_q + (size_t)blk * IN * IN;
        const float* p_wk   = w_k + (size_t)blk * IN * IN;
        const float* p_wv   = w_v + (size_t)blk * IN * IN;
        const float* p_wig  = w_ig + (size_t)blk * IN * NHh;
        const float* p_big  = b_ig + (size_t)blk * NHh;
        const float* p_wfg  = w_fg + (size_t)blk * IN * NHh;
        const float* p_bfg  = b_fg + (size_t)blk * NHh;
        const float* p_hns  = hn_s + (size_t)blk * NHh * DHd;
        const float* p_wd   = w_down + (size_t)blk * IN * Dm;
        const float* p_bd   = b_down + (size_t)blk * Dm;

        ln_kernel<<<ROWS, 256, 0, stream>>>(f_h, p_ln_s, p_ln_b, f_xn);

        gemm_kernel<<<dim3(2 * IN / 64, (ROWS + 63) / 64), 256, 0, stream>>>(
            f_xn, Dm, p_wup, 2 * IN, p_bup, nullptr, 0, f_up, 2 * IN, ROWS, Dm, 1.f);

        conv_silu_kernel<<<(ROWS * IN + 255) / 256, 256, 0, stream>>>(f_up, p_ck, p_cb, f_xc);

        gemm_kernel<<<dim3(IN / 64, (ROWS + 63) / 64), 256, 0, stream>>>(
            f_xc, IN, p_wq, IN, nullptr, nullptr, 0, f_q, IN, ROWS, IN, 1.f);
        gemm_kernel<<<dim3(IN / 64, (ROWS + 63) / 64), 256, 0, stream>>>(
            f_xc, IN, p_wk, IN, nullptr, nullptr, 0, f_k, IN, ROWS, IN, kscale);
        gemm_kernel<<<dim3(IN / 64, (ROWS + 63) / 64), 256, 0, stream>>>(
            f_up, 2 * IN, p_wv, IN, nullptr, nullptr, 0, f_v, IN, ROWS, IN, 1.f);

        gates_kernel<<<ROWS, 256, 0, stream>>>(f_xc, p_wig, p_big, p_wfg, p_bfg, f_ip, f_fp);

        scan_kernel<<<Bsz * NHh, 256, 0, stream>>>(f_q, f_k, f_v, f_ip, f_fp, f_hs);

        headnorm_kernel<<<ROWS * NHh, 64, 0, stream>>>(f_hs, p_hns, f_up, f_xc);

        gemm_kernel<<<dim3(Dm / 64, (ROWS + 63) / 64), 256, 0, stream>>>(
            f_xc, IN, p_wd, Dm, p_bd, f_h, Dm, f_h, Dm, ROWS, IN, 1.f);
    }

    classifier_kernel<<<Bsz, 256, 0, stream>>>(f_h, fcls, fclb, fc_w, fc_b, out);
}